// Round 13
// baseline (797.242 us; speedup 1.0000x reference)
//
#include <hip/hip_runtime.h>
#include <cstdint>
#include <cstddef>

#define EPSF 1e-8f

typedef __attribute__((ext_vector_type(8))) short bf16x8;
typedef __attribute__((ext_vector_type(4))) float f32x4;
typedef unsigned short ushort_t;

static __device__ __forceinline__ ushort_t f2bf(float f) {
  unsigned u = __builtin_bit_cast(unsigned, f);
  unsigned r = (u + 0x7FFFu + ((u >> 16) & 1u)) >> 16;
  return (ushort_t)r;
}
static __device__ __forceinline__ float bf2f(ushort_t h) {
  return __builtin_bit_cast(float, (unsigned)h << 16);
}

// ---------------- conv1 -> h2x[pix][b][ciblk(8)][hi32|lo32] bf16
__global__ __launch_bounds__(256) void conv1_kernel(
    const float* __restrict__ x, const float* __restrict__ cw,
    const float* __restrict__ cb, ushort_t* __restrict__ h2x)
{
  int oy = blockIdx.x, b = blockIdx.y, ci = threadIdx.x;
  float w[81];
#pragma unroll
  for (int i = 0; i < 81; ++i) w[i] = cw[ci * 81 + i];
  float bias = cb[ci];
  float acc[20];
#pragma unroll
  for (int ox = 0; ox < 20; ++ox) acc[ox] = bias;
  const float* xb = x + (size_t)b * 784;
  for (int ky = 0; ky < 9; ++ky) {
    const float* row = xb + (oy + ky) * 28;  // uniform address -> scalar loads
    float rv[28];
#pragma unroll
    for (int c = 0; c < 28; ++c) rv[c] = row[c];
#pragma unroll
    for (int kx = 0; kx < 9; ++kx) {
      float wv = w[ky * 9 + kx];
#pragma unroll
      for (int ox = 0; ox < 20; ++ox)
        acc[ox] = fmaf(rv[ox + kx], wv, acc[ox]);
    }
  }
  int cblk = ci >> 5, jj = ci & 31;
#pragma unroll
  for (int ox = 0; ox < 20; ++ox) {
    float a = fmaxf(acc[ox], 0.f);
    ushort_t hi = f2bf(a);
    ushort_t lo = f2bf(a - bf2f(hi));
    size_t o = ((size_t)(oy * 20 + ox) * 256 + b) * 512 + cblk * 64 + jj;
    h2x[o] = hi; h2x[o + 32] = lo;
  }
}

// ---------------- w2k prep: c1w[co][ci][81tap] -> w2k[co][tap][ciblk][hi32|lo32]
__global__ __launch_bounds__(256) void w2k_prep_kernel(
    const float* __restrict__ c1w, ushort_t* __restrict__ w2k)
{
  int co = blockIdx.x, ci = threadIdx.x;
  const float* src = c1w + ((size_t)co * 256 + ci) * 81;
  int cblk = ci >> 5, jj = ci & 31;
  for (int tap = 0; tap < 81; ++tap) {
    float v = src[tap];
    ushort_t hi = f2bf(v);
    size_t dst = ((size_t)co * 81 + tap) * 512 + cblk * 64 + jj;
    w2k[dst] = hi;
    w2k[dst + 32] = f2bf(v - bf2f(hi));
  }
}

// ---------------- caps1 GEMM, 3-term split-bf16, BK=32 dbuf counted-vmcnt (round-12 proven).
__global__ __launch_bounds__(256, 2) void caps1_mfma_kernel(
    const ushort_t* __restrict__ h2x, const ushort_t* __restrict__ w2k,
    float* __restrict__ partial)
{
  int bid = blockIdx.x;
  int ks = bid & 3;
  int nt = (bid >> 2) & 1;
  int kt = (bid >> 3) & 1;
  int mt = (bid >> 4) & 1;
  int pos = bid >> 5;                 // 0..35
  int ys = pos / 6, xs = pos % 6;
  int t = threadIdx.x;
  int wid = t >> 6, lane = t & 63;
  int wr = wid >> 1, wc = wid & 1;    // 2x2 waves, wave tile 64x64
  int lrow = lane & 15, g = lane >> 4;

  int b0 = mt * 128, n0 = nt * 128;
  int tb    = kt ? 41 : 0;
  int ntaps = kt ? 40 : 41;
  int nht   = 2 * ntaps;

  __shared__ ushort_t lds[2][2][128 * 64];

  f32x4 acc[4][4];
#pragma unroll
  for (int i = 0; i < 4; ++i)
#pragma unroll
    for (int j = 0; j < 4; ++j) acc[i][j] = (f32x4){0.f, 0.f, 0.f, 0.f};

  int c_ = (t & 7) ^ ((t >> 3) & 7);
  size_t aRowB[4], bRow81[4];
  int ldsBase[4];
#pragma unroll
  for (int i = 0; i < 4; ++i) {
    int row = i * 32 + (t >> 3);
    aRowB[i]  = (size_t)(b0 + row) * 512 + ks * 128 + c_ * 8;
    bRow81[i] = (size_t)(n0 + row) * 81;
    ldsBase[i] = (i * 32 + wid * 8) * 64;
  }

  auto stage = [&](int j, int bufi) {
    int tap = tb + (j >> 1);
    int half = j & 1;
    int ky = tap / 9, kx = tap - ky * 9;
    int pix = (2 * ys + ky) * 20 + 2 * xs + kx;
    size_t apix = (size_t)pix * 131072 + half * 64;
    int sub = ks * 128 + half * 64 + c_ * 8;
#pragma unroll
    for (int i = 0; i < 4; ++i) {
      const ushort_t* ga = h2x + apix + aRowB[i];
      const ushort_t* gb = w2k + (bRow81[i] + tap) * 512 + sub;
      __builtin_amdgcn_global_load_lds(ga, &lds[bufi][0][ldsBase[i]], 16, 0, 0);
      __builtin_amdgcn_global_load_lds(gb, &lds[bufi][1][ldsBase[i]], 16, 0, 0);
    }
  };

  bf16x8 a_h[4], a_l[4], b_h[4], b_l[4];
  auto read_frags = [&](int bufi) {
    const ushort_t* LA = &lds[bufi][0][0];
    const ushort_t* LB = &lds[bufi][1][0];
#pragma unroll
    for (int f = 0; f < 4; ++f) {
      int ra = wr * 64 + f * 16 + lrow;
      int sa = ra * 64;
      a_h[f] = *(const bf16x8*)(LA + sa + ((g)     ^ (ra & 7)) * 8);
      a_l[f] = *(const bf16x8*)(LA + sa + ((4 + g) ^ (ra & 7)) * 8);
      int rb = wc * 64 + f * 16 + lrow;
      int sb = rb * 64;
      b_h[f] = *(const bf16x8*)(LB + sb + ((g)     ^ (rb & 7)) * 8);
      b_l[f] = *(const bf16x8*)(LB + sb + ((4 + g) ^ (rb & 7)) * 8);
    }
  };

  stage(0, 0);
  stage(1, 1);
  asm volatile("s_waitcnt vmcnt(8)" ::: "memory");
  __builtin_amdgcn_sched_barrier(0);
  __builtin_amdgcn_s_barrier();

  for (int j = 0; j < nht; ++j) {
    int cur = j & 1;
    read_frags(cur);
    asm volatile("s_waitcnt lgkmcnt(0)" ::: "memory");
    __builtin_amdgcn_sched_barrier(0);
    __builtin_amdgcn_s_barrier();            // #1: all waves done reading buf[cur]

    if (j + 2 < nht) stage(j + 2, cur);
    __builtin_amdgcn_sched_barrier(0);

    __builtin_amdgcn_s_setprio(1);
#pragma unroll
    for (int mf = 0; mf < 4; ++mf)
#pragma unroll
      for (int nf = 0; nf < 4; ++nf) {
        acc[mf][nf] = __builtin_amdgcn_mfma_f32_16x16x32_bf16(a_h[mf], b_h[nf], acc[mf][nf], 0, 0, 0);
        acc[mf][nf] = __builtin_amdgcn_mfma_f32_16x16x32_bf16(a_h[mf], b_l[nf], acc[mf][nf], 0, 0, 0);
        acc[mf][nf] = __builtin_amdgcn_mfma_f32_16x16x32_bf16(a_l[mf], b_h[nf], acc[mf][nf], 0, 0, 0);
      }
    __builtin_amdgcn_s_setprio(0);
    __builtin_amdgcn_sched_barrier(0);

    if (j + 2 < nht) { asm volatile("s_waitcnt vmcnt(8)" ::: "memory"); }
    else             { asm volatile("s_waitcnt vmcnt(0)" ::: "memory"); }
    __builtin_amdgcn_sched_barrier(0);
    __builtin_amdgcn_s_barrier();            // #2: buf[cur^1] staged & visible
  }

  float* pp = partial + (size_t)(kt * 4 + ks) * 2359296;
#pragma unroll
  for (int mf = 0; mf < 4; ++mf) {
    int m = b0 + wr * 64 + mf * 16 + g * 4;
#pragma unroll
    for (int nf = 0; nf < 4; ++nf) {
      int n = n0 + wc * 64 + nf * 16 + lrow;
#pragma unroll
      for (int r = 0; r < 4; ++r)
        pp[((size_t)(pos * 256 + m + r)) * 256 + n] = acc[mf][nf][r];
    }
  }
}

// ---------------- combine 8 K-slices + bias + squash -> u[b][1152][8]
__global__ __launch_bounds__(256) void combine_kernel(
    const float* __restrict__ partial, const float* __restrict__ c1b, float* __restrict__ u)
{
  int gidx = blockIdx.x * 256 + threadIdx.x;  // < 294912
  int caps = gidx & 31;
  int b = (gidx >> 5) & 255;
  int pos = gidx >> 13;
  int ys = pos / 6, xs = pos % 6;
  size_t base = ((size_t)pos * 256 + b) * 256 + caps * 8;
  f32x4 s0 = {0.f, 0.f, 0.f, 0.f}, s1 = {0.f, 0.f, 0.f, 0.f};
#pragma unroll
  for (int ksp = 0; ksp < 8; ++ksp) {
    const float* pp = partial + (size_t)ksp * 2359296 + base;
    s0 += *(const f32x4*)pp;
    s1 += *(const f32x4*)(pp + 4);
  }
  const float* bp = c1b + caps * 8;
#pragma unroll
  for (int i = 0; i < 4; ++i) { s0[i] += bp[i]; s1[i] += bp[4 + i]; }
  float sq = s0[0]*s0[0] + s0[1]*s0[1] + s0[2]*s0[2] + s0[3]*s0[3]
           + s1[0]*s1[0] + s1[1]*s1[1] + s1[2]*s1[2] + s1[3]*s1[3];
  float scale = sq / ((1.f + sq) * sqrtf(sq + EPSF));
  int nvec = ys * 192 + caps * 6 + xs;
  float* up = u + ((size_t)b * 1152 + nvec) * 8;
  f32x4 o0, o1;
#pragma unroll
  for (int i = 0; i < 4; ++i) { o0[i] = s0[i] * scale; o1[i] = s1[i] * scale; }
  *(f32x4*)up = o0;
  *(f32x4*)(up + 4) = o1;
}

// ---------------- FUSED routing: computes xh on the fly (no 189MB xhat round-trip).
// grid 2560, bid%8 pins class c to one XCD -> W2_c (589KB) L2-resident, 10x reuse.
// Dense f32x4 W2 loads (thread's W2 row = 128 contiguous floats), dual accumulators (ILP 8).
__global__ __launch_bounds__(256) void routing_kernel(
    const float* __restrict__ u, const float* __restrict__ W2, float* __restrict__ vout)
{
  int bid = blockIdx.x;
  int c, b;
  if (bid < 2048) { c = bid & 7; b = bid >> 3; }
  else { int r = bid - 2048; int x = r & 7; c = 8 + (x >> 2); b = (r >> 3) * 4 + (x & 3); }
  int t = threadIdx.x;
  int wid = t >> 6, lane = t & 63;
  float xh[5][16];
  float bn[5] = {0, 0, 0, 0, 0};
  bool valid[5];
  const float* ub = u + (size_t)b * 9216;
  const float* Wc = W2 + (size_t)c * 147456;   // 1152*128
#pragma unroll
  for (int j = 0; j < 5; ++j) {
    int n = t + 256 * j;
    valid[j] = (n < 1152);
    if (valid[j]) {
      float uv[8];
      *(f32x4*)&uv[0] = *(const f32x4*)(ub + (size_t)n * 8);
      *(f32x4*)&uv[4] = *(const f32x4*)(ub + (size_t)n * 8 + 4);
      const float* wn = Wc + (size_t)n * 128;
#pragma unroll
      for (int oc = 0; oc < 4; ++oc) {
        f32x4 a0 = {0.f, 0.f, 0.f, 0.f}, a1 = {0.f, 0.f, 0.f, 0.f};
#pragma unroll
        for (int i = 0; i < 4; ++i) {
          f32x4 w0 = *(const f32x4*)(wn + (2 * i) * 16 + oc * 4);
          f32x4 w1 = *(const f32x4*)(wn + (2 * i + 1) * 16 + oc * 4);
          a0 += uv[2 * i] * w0;
          a1 += uv[2 * i + 1] * w1;
        }
        f32x4 s = a0 + a1;
#pragma unroll
        for (int k = 0; k < 4; ++k) xh[j][oc * 4 + k] = s[k];
      }
    } else {
#pragma unroll
      for (int o = 0; o < 16; ++o) xh[j][o] = 0.f;
    }
  }
  __shared__ float redm[4], redz[4], reds[64], sv[16];
  float scale = 0.f;
  for (int it = 0; it < 3; ++it) {
    float m = -1e30f;
#pragma unroll
    for (int j = 0; j < 5; ++j) if (valid[j]) m = fmaxf(m, bn[j]);
    for (int d = 1; d < 64; d <<= 1) m = fmaxf(m, __shfl_xor(m, d));
    if (lane == 0) redm[wid] = m;
    __syncthreads();
    m = fmaxf(fmaxf(redm[0], redm[1]), fmaxf(redm[2], redm[3]));
    float e[5]; float z = 0.f;
#pragma unroll
    for (int j = 0; j < 5; ++j) { e[j] = valid[j] ? expf(bn[j] - m) : 0.f; z += e[j]; }
    for (int d = 1; d < 64; d <<= 1) z += __shfl_xor(z, d);
    if (lane == 0) redz[wid] = z;
    __syncthreads();
    z = redz[0] + redz[1] + redz[2] + redz[3];
    float ps[16];
#pragma unroll
    for (int o = 0; o < 16; ++o) ps[o] = 0.f;
#pragma unroll
    for (int j = 0; j < 5; ++j)
#pragma unroll
      for (int o = 0; o < 16; ++o) ps[o] = fmaf(e[j], xh[j][o], ps[o]);
#pragma unroll
    for (int o = 0; o < 16; ++o) {
      float vv = ps[o];
      for (int d = 1; d < 64; d <<= 1) vv += __shfl_xor(vv, d);
      if (lane == 0) reds[wid * 16 + o] = vv;
    }
    __syncthreads();
    if (t < 16) sv[t] = (reds[t] + reds[16 + t] + reds[32 + t] + reds[48 + t]) / z;
    __syncthreads();
    float vsc[16]; float sq = 0.f;
#pragma unroll
    for (int o = 0; o < 16; ++o) { vsc[o] = sv[o]; sq += sv[o] * sv[o]; }
    scale = sq / ((1.f + sq) * sqrtf(sq + EPSF));
    if (it < 2) {
#pragma unroll
      for (int j = 0; j < 5; ++j) if (valid[j]) {
        float dot = 0.f;
#pragma unroll
        for (int o = 0; o < 16; ++o) dot = fmaf(xh[j][o], vsc[o] * scale, dot);
        bn[j] += dot;
      }
    }
    __syncthreads();
  }
  if (t < 16) vout[((size_t)c * 256 + b) * 16 + t] = sv[t] * scale;
}

// ---------------- class scores, softmax, argmax(first-max), mask. grid 256 (b).
__global__ __launch_bounds__(256) void classify_kernel(
    const float* __restrict__ v, float* __restrict__ probs, float* __restrict__ masked)
{
  int b = blockIdx.x, t = threadIdx.x;
  __shared__ float sc[10], vv[160];
  int c = t >> 4, o = t & 15;
  float val = 0.f;
  if (t < 160) { val = v[((size_t)c * 256 + b) * 16 + o]; vv[t] = val; }
  float sq = val * val;
  sq += __shfl_xor(sq, 1); sq += __shfl_xor(sq, 2);
  sq += __shfl_xor(sq, 4); sq += __shfl_xor(sq, 8);
  if (t < 160 && o == 0) sc[c] = sqrtf(sq + EPSF);
  __syncthreads();
  float m = sc[0];
#pragma unroll
  for (int i = 1; i < 10; ++i) m = fmaxf(m, sc[i]);
  float ee[10]; float Z = 0.f;
#pragma unroll
  for (int i = 0; i < 10; ++i) { ee[i] = expf(sc[i] - m); Z += ee[i]; }
  float p[10];
#pragma unroll
  for (int i = 0; i < 10; ++i) p[i] = ee[i] / Z;
  int label = 0; float best = p[0];
#pragma unroll
  for (int i = 1; i < 10; ++i) if (p[i] > best) { best = p[i]; label = i; }
  if (t < 10) probs[(size_t)b * 10 + t] = p[t];
  if (t < 160) masked[(size_t)b * 160 + t] = (c == label) ? vv[t] : 0.f;
}

// ---------------- decoder GEMM: C[M=256,N] = act(A[M,K] @ W[K,N] + bias). ACT 0=relu 1=sigmoid
template <int ACT>
__global__ __launch_bounds__(256) void mlp_kernel(
    const float* __restrict__ A, const float* __restrict__ W,
    const float* __restrict__ bias, float* __restrict__ C, int N, int K)
{
  int j = blockIdx.x * 64 + (threadIdx.x & 63);
  int ty = threadIdx.x >> 6;
  int m0 = blockIdx.y * 16;
  __shared__ float As[16][33];
  float acc[4] = {0.f, 0.f, 0.f, 0.f};
  for (int k0 = 0; k0 < K; k0 += 32) {
    for (int e = threadIdx.x; e < 512; e += 256) {
      int r = e >> 5, kk = e & 31;
      As[r][kk] = A[(size_t)(m0 + r) * K + k0 + kk];
    }
    __syncthreads();
    if (j < N) {
      for (int kk = 0; kk < 32; ++kk) {
        float wv = W[(size_t)(k0 + kk) * N + j];
#pragma unroll
        for (int r = 0; r < 4; ++r) acc[r] = fmaf(As[ty + 4 * r][kk], wv, acc[r]);
      }
    }
    __syncthreads();
  }
  if (j < N) {
    float bv = bias[j];
#pragma unroll
    for (int r = 0; r < 4; ++r) {
      float xx = acc[r] + bv;
      if (ACT == 0) xx = fmaxf(xx, 0.f);
      else xx = 1.f / (1.f + expf(-xx));
      C[(size_t)(m0 + ty + 4 * r) * N + j] = xx;
    }
  }
}

extern "C" void kernel_launch(void* const* d_in, const int* in_sizes, int n_in,
                              void* d_out, int out_size, void* d_ws, size_t ws_size,
                              hipStream_t stream)
{
  const float* x   = (const float*)d_in[0];
  const float* cw  = (const float*)d_in[1];
  const float* cb  = (const float*)d_in[2];
  const float* c1w = (const float*)d_in[3];
  const float* c1b = (const float*)d_in[4];
  const float* c2w = (const float*)d_in[5];
  const float* w1  = (const float*)d_in[6];
  const float* b1  = (const float*)d_in[7];
  const float* w2  = (const float*)d_in[8];
  const float* b2  = (const float*)d_in[9];
  const float* w3  = (const float*)d_in[10];
  const float* b3  = (const float*)d_in[11];
  float* out = (float*)d_out;

  char* p = (char*)d_ws;
  ushort_t* h2x = (ushort_t*)p; p += (size_t)52428800 * 2;   // 400*256*512 (pix-major)
  ushort_t* w2k = (ushort_t*)p; p += (size_t)10616832 * 2;   // 256*81*512
  float* partial = (float*)p;   p += (size_t)8 * 2359296 * 4;
  float* u       = (float*)p;   p += (size_t)2359296 * 4;
  float* v       = (float*)p;   p += (size_t)40960 * 4;
  float* masked  = (float*)p;   p += (size_t)40960 * 4;
  float* a1      = (float*)p;   p += (size_t)131072 * 4;
  float* a2      = (float*)p;   p += (size_t)262144 * 4;

  hipLaunchKernelGGL(w2k_prep_kernel, dim3(256), dim3(256), 0, stream, c1w, w2k);
  hipLaunchKernelGGL(conv1_kernel, dim3(20, 256), dim3(256), 0, stream, x, cw, cb, h2x);
  hipLaunchKernelGGL(caps1_mfma_kernel, dim3(1152), dim3(256), 0, stream, h2x, w2k, partial);
  hipLaunchKernelGGL(combine_kernel, dim3(1152), dim3(256), 0, stream, partial, c1b, u);
  hipLaunchKernelGGL(routing_kernel, dim3(2560), dim3(256), 0, stream, u, c2w, v);
  hipLaunchKernelGGL(classify_kernel, dim3(256), dim3(256), 0, stream, v, out, masked);
  hipLaunchKernelGGL(mlp_kernel<0>, dim3(8, 16), dim3(256), 0, stream, masked, w1, b1, a1, 512, 160);
  hipLaunchKernelGGL(mlp_kernel<0>, dim3(16, 16), dim3(256), 0, stream, a1, w2, b2, a2, 1024, 512);
  hipLaunchKernelGGL(mlp_kernel<1>, dim3(13, 16), dim3(256), 0, stream, a2, w3, b3, out + 2560, 784, 1024);
}

// Round 14
// 581.923 us; speedup vs baseline: 1.3700x; 1.3700x over previous
//
#include <hip/hip_runtime.h>
#include <cstdint>
#include <cstddef>

#define EPSF 1e-8f

typedef __attribute__((ext_vector_type(8))) short bf16x8;
typedef __attribute__((ext_vector_type(4))) float f32x4;
typedef unsigned short ushort_t;

static __device__ __forceinline__ ushort_t f2bf(float f) {
  unsigned u = __builtin_bit_cast(unsigned, f);
  unsigned r = (u + 0x7FFFu + ((u >> 16) & 1u)) >> 16;
  return (ushort_t)r;
}
static __device__ __forceinline__ float bf2f(ushort_t h) {
  return __builtin_bit_cast(float, (unsigned)h << 16);
}

// ---------------- conv1 -> h2x[pix][b][ciblk(8)][hi32|lo32] bf16
__global__ __launch_bounds__(256) void conv1_kernel(
    const float* __restrict__ x, const float* __restrict__ cw,
    const float* __restrict__ cb, ushort_t* __restrict__ h2x)
{
  int oy = blockIdx.x, b = blockIdx.y, ci = threadIdx.x;
  float w[81];
#pragma unroll
  for (int i = 0; i < 81; ++i) w[i] = cw[ci * 81 + i];
  float bias = cb[ci];
  float acc[20];
#pragma unroll
  for (int ox = 0; ox < 20; ++ox) acc[ox] = bias;
  const float* xb = x + (size_t)b * 784;
  for (int ky = 0; ky < 9; ++ky) {
    const float* row = xb + (oy + ky) * 28;  // uniform address -> scalar loads
    float rv[28];
#pragma unroll
    for (int c = 0; c < 28; ++c) rv[c] = row[c];
#pragma unroll
    for (int kx = 0; kx < 9; ++kx) {
      float wv = w[ky * 9 + kx];
#pragma unroll
      for (int ox = 0; ox < 20; ++ox)
        acc[ox] = fmaf(rv[ox + kx], wv, acc[ox]);
    }
  }
  int cblk = ci >> 5, jj = ci & 31;
#pragma unroll
  for (int ox = 0; ox < 20; ++ox) {
    float a = fmaxf(acc[ox], 0.f);
    ushort_t hi = f2bf(a);
    ushort_t lo = f2bf(a - bf2f(hi));
    size_t o = ((size_t)(oy * 20 + ox) * 256 + b) * 512 + cblk * 64 + jj;
    h2x[o] = hi; h2x[o + 32] = lo;
  }
}

// ---------------- w2k prep: c1w[co][ci][81tap] -> w2k[co][tap][ciblk][hi32|lo32]
__global__ __launch_bounds__(256) void w2k_prep_kernel(
    const float* __restrict__ c1w, ushort_t* __restrict__ w2k)
{
  int co = blockIdx.x, ci = threadIdx.x;
  const float* src = c1w + ((size_t)co * 256 + ci) * 81;
  int cblk = ci >> 5, jj = ci & 31;
  for (int tap = 0; tap < 81; ++tap) {
    float v = src[tap];
    ushort_t hi = f2bf(v);
    size_t dst = ((size_t)co * 81 + tap) * 512 + cblk * 64 + jj;
    w2k[dst] = hi;
    w2k[dst + 32] = f2bf(v - bf2f(hi));
  }
}

// ---------------- caps1 GEMM, 3-term split-bf16, BK=32 dbuf counted-vmcnt (round-12 proven).
__global__ __launch_bounds__(256, 2) void caps1_mfma_kernel(
    const ushort_t* __restrict__ h2x, const ushort_t* __restrict__ w2k,
    float* __restrict__ partial)
{
  int bid = blockIdx.x;
  int ks = bid & 3;
  int nt = (bid >> 2) & 1;
  int kt = (bid >> 3) & 1;
  int mt = (bid >> 4) & 1;
  int pos = bid >> 5;                 // 0..35
  int ys = pos / 6, xs = pos % 6;
  int t = threadIdx.x;
  int wid = t >> 6, lane = t & 63;
  int wr = wid >> 1, wc = wid & 1;    // 2x2 waves, wave tile 64x64
  int lrow = lane & 15, g = lane >> 4;

  int b0 = mt * 128, n0 = nt * 128;
  int tb    = kt ? 41 : 0;
  int ntaps = kt ? 40 : 41;
  int nht   = 2 * ntaps;

  __shared__ ushort_t lds[2][2][128 * 64];

  f32x4 acc[4][4];
#pragma unroll
  for (int i = 0; i < 4; ++i)
#pragma unroll
    for (int j = 0; j < 4; ++j) acc[i][j] = (f32x4){0.f, 0.f, 0.f, 0.f};

  int c_ = (t & 7) ^ ((t >> 3) & 7);
  size_t aRowB[4], bRow81[4];
  int ldsBase[4];
#pragma unroll
  for (int i = 0; i < 4; ++i) {
    int row = i * 32 + (t >> 3);
    aRowB[i]  = (size_t)(b0 + row) * 512 + ks * 128 + c_ * 8;
    bRow81[i] = (size_t)(n0 + row) * 81;
    ldsBase[i] = (i * 32 + wid * 8) * 64;
  }

  auto stage = [&](int j, int bufi) {
    int tap = tb + (j >> 1);
    int half = j & 1;
    int ky = tap / 9, kx = tap - ky * 9;
    int pix = (2 * ys + ky) * 20 + 2 * xs + kx;
    size_t apix = (size_t)pix * 131072 + half * 64;
    int sub = ks * 128 + half * 64 + c_ * 8;
#pragma unroll
    for (int i = 0; i < 4; ++i) {
      const ushort_t* ga = h2x + apix + aRowB[i];
      const ushort_t* gb = w2k + (bRow81[i] + tap) * 512 + sub;
      __builtin_amdgcn_global_load_lds(ga, &lds[bufi][0][ldsBase[i]], 16, 0, 0);
      __builtin_amdgcn_global_load_lds(gb, &lds[bufi][1][ldsBase[i]], 16, 0, 0);
    }
  };

  bf16x8 a_h[4], a_l[4], b_h[4], b_l[4];
  auto read_frags = [&](int bufi) {
    const ushort_t* LA = &lds[bufi][0][0];
    const ushort_t* LB = &lds[bufi][1][0];
#pragma unroll
    for (int f = 0; f < 4; ++f) {
      int ra = wr * 64 + f * 16 + lrow;
      int sa = ra * 64;
      a_h[f] = *(const bf16x8*)(LA + sa + ((g)     ^ (ra & 7)) * 8);
      a_l[f] = *(const bf16x8*)(LA + sa + ((4 + g) ^ (ra & 7)) * 8);
      int rb = wc * 64 + f * 16 + lrow;
      int sb = rb * 64;
      b_h[f] = *(const bf16x8*)(LB + sb + ((g)     ^ (rb & 7)) * 8);
      b_l[f] = *(const bf16x8*)(LB + sb + ((4 + g) ^ (rb & 7)) * 8);
    }
  };

  stage(0, 0);
  stage(1, 1);
  asm volatile("s_waitcnt vmcnt(8)" ::: "memory");
  __builtin_amdgcn_sched_barrier(0);
  __builtin_amdgcn_s_barrier();

  for (int j = 0; j < nht; ++j) {
    int cur = j & 1;
    read_frags(cur);
    asm volatile("s_waitcnt lgkmcnt(0)" ::: "memory");
    __builtin_amdgcn_sched_barrier(0);
    __builtin_amdgcn_s_barrier();            // #1: all waves done reading buf[cur]

    if (j + 2 < nht) stage(j + 2, cur);
    __builtin_amdgcn_sched_barrier(0);

    __builtin_amdgcn_s_setprio(1);
#pragma unroll
    for (int mf = 0; mf < 4; ++mf)
#pragma unroll
      for (int nf = 0; nf < 4; ++nf) {
        acc[mf][nf] = __builtin_amdgcn_mfma_f32_16x16x32_bf16(a_h[mf], b_h[nf], acc[mf][nf], 0, 0, 0);
        acc[mf][nf] = __builtin_amdgcn_mfma_f32_16x16x32_bf16(a_h[mf], b_l[nf], acc[mf][nf], 0, 0, 0);
        acc[mf][nf] = __builtin_amdgcn_mfma_f32_16x16x32_bf16(a_l[mf], b_h[nf], acc[mf][nf], 0, 0, 0);
      }
    __builtin_amdgcn_s_setprio(0);
    __builtin_amdgcn_sched_barrier(0);

    if (j + 2 < nht) { asm volatile("s_waitcnt vmcnt(8)" ::: "memory"); }
    else             { asm volatile("s_waitcnt vmcnt(0)" ::: "memory"); }
    __builtin_amdgcn_sched_barrier(0);
    __builtin_amdgcn_s_barrier();            // #2: buf[cur^1] staged & visible
  }

  float* pp = partial + (size_t)(kt * 4 + ks) * 2359296;
#pragma unroll
  for (int mf = 0; mf < 4; ++mf) {
    int m = b0 + wr * 64 + mf * 16 + g * 4;
#pragma unroll
    for (int nf = 0; nf < 4; ++nf) {
      int n = n0 + wc * 64 + nf * 16 + lrow;
#pragma unroll
      for (int r = 0; r < 4; ++r)
        pp[((size_t)(pos * 256 + m + r)) * 256 + n] = acc[mf][nf][r];
    }
  }
}

// ---------------- combine 8 K-slices + bias + squash -> u[b][1152][8]
__global__ __launch_bounds__(256) void combine_kernel(
    const float* __restrict__ partial, const float* __restrict__ c1b, float* __restrict__ u)
{
  int gidx = blockIdx.x * 256 + threadIdx.x;  // < 294912
  int caps = gidx & 31;
  int b = (gidx >> 5) & 255;
  int pos = gidx >> 13;
  int ys = pos / 6, xs = pos % 6;
  size_t base = ((size_t)pos * 256 + b) * 256 + caps * 8;
  f32x4 s0 = {0.f, 0.f, 0.f, 0.f}, s1 = {0.f, 0.f, 0.f, 0.f};
#pragma unroll
  for (int ksp = 0; ksp < 8; ++ksp) {
    const float* pp = partial + (size_t)ksp * 2359296 + base;
    s0 += *(const f32x4*)pp;
    s1 += *(const f32x4*)(pp + 4);
  }
  const float* bp = c1b + caps * 8;
#pragma unroll
  for (int i = 0; i < 4; ++i) { s0[i] += bp[i]; s1[i] += bp[4 + i]; }
  float sq = s0[0]*s0[0] + s0[1]*s0[1] + s0[2]*s0[2] + s0[3]*s0[3]
           + s1[0]*s1[0] + s1[1]*s1[1] + s1[2]*s1[2] + s1[3]*s1[3];
  float scale = sq / ((1.f + sq) * sqrtf(sq + EPSF));
  int nvec = ys * 192 + caps * 6 + xs;
  float* up = u + ((size_t)b * 1152 + nvec) * 8;
  f32x4 o0, o1;
#pragma unroll
  for (int i = 0; i < 4; ++i) { o0[i] = s0[i] * scale; o1[i] = s1[i] * scale; }
  *(f32x4*)up = o0;
  *(f32x4*)(up + 4) = o1;
}

// ---------------- xhat: xh[c][b][n][o] = sum_i u[b][n][i] * W2[c][n][i][o]
// thread map (c = t>>5, nh = (t>>4)&1, o = t&15): 32 consecutive lanes write 128B contiguous.
__global__ __launch_bounds__(320) void xhat_kernel(
    const float* __restrict__ u, const float* __restrict__ W2, float* __restrict__ xh)
{
  int np = blockIdx.x;           // n = np*2 + nh
  int t = threadIdx.x;
  int c  = t >> 5;
  int nh = (t >> 4) & 1;
  int o  = t & 15;
  int n = np * 2 + nh;
  __shared__ float us[2][256][8];
  for (int e = t; e < 4096; e += 320) {
    int b = e >> 4;
    int nn = (e >> 3) & 1, i = e & 7;
    us[nn][b][i] = u[((size_t)b * 1152 + np * 2 + nn) * 8 + i];
  }
  __syncthreads();
  float wcol[8];
  const float* wp = W2 + (((size_t)c * 1152 + n) * 8) * 16 + o;
#pragma unroll
  for (int i = 0; i < 8; ++i) wcol[i] = wp[i * 16];
  float* xp = xh + ((size_t)(c * 256) * 1152 + n) * 16 + o;
  for (int b = 0; b < 256; ++b) {
    float s = 0.f;
#pragma unroll
    for (int i = 0; i < 8; ++i) s = fmaf(us[nh][b][i], wcol[i], s);
    xp[(size_t)b * 1152 * 16] = s;
  }
}

// ---------------- dynamic routing, per-(c,b), x_hat pre-materialized. grid (256 b, 10 c).
__global__ __launch_bounds__(256) void routing_kernel(
    const float* __restrict__ xhat, float* __restrict__ vout)
{
  int b = blockIdx.x, c = blockIdx.y, t = threadIdx.x;
  int wid = t >> 6, lane = t & 63;
  float xh[5][16];
  float bn[5] = {0, 0, 0, 0, 0};
  bool valid[5];
  const float* xp = xhat + ((size_t)(c * 256 + b)) * 1152 * 16;
#pragma unroll
  for (int j = 0; j < 5; ++j) {
    int n = t + 256 * j;
    valid[j] = (n < 1152);
    if (valid[j]) {
      const f32x4* q = (const f32x4*)(xp + (size_t)n * 16);
#pragma unroll
      for (int v4 = 0; v4 < 4; ++v4) {
        f32x4 val = q[v4];
#pragma unroll
        for (int k = 0; k < 4; ++k) xh[j][v4 * 4 + k] = val[k];
      }
    } else {
#pragma unroll
      for (int o = 0; o < 16; ++o) xh[j][o] = 0.f;
    }
  }
  __shared__ float redm[4], redz[4], reds[64], sv[16];
  float scale = 0.f;
  for (int it = 0; it < 3; ++it) {
    float m = -1e30f;
#pragma unroll
    for (int j = 0; j < 5; ++j) if (valid[j]) m = fmaxf(m, bn[j]);
    for (int d = 1; d < 64; d <<= 1) m = fmaxf(m, __shfl_xor(m, d));
    if (lane == 0) redm[wid] = m;
    __syncthreads();
    m = fmaxf(fmaxf(redm[0], redm[1]), fmaxf(redm[2], redm[3]));
    float e[5]; float z = 0.f;
#pragma unroll
    for (int j = 0; j < 5; ++j) { e[j] = valid[j] ? expf(bn[j] - m) : 0.f; z += e[j]; }
    for (int d = 1; d < 64; d <<= 1) z += __shfl_xor(z, d);
    if (lane == 0) redz[wid] = z;
    __syncthreads();
    z = redz[0] + redz[1] + redz[2] + redz[3];
    float ps[16];
#pragma unroll
    for (int o = 0; o < 16; ++o) ps[o] = 0.f;
#pragma unroll
    for (int j = 0; j < 5; ++j)
#pragma unroll
      for (int o = 0; o < 16; ++o) ps[o] = fmaf(e[j], xh[j][o], ps[o]);
#pragma unroll
    for (int o = 0; o < 16; ++o) {
      float vv = ps[o];
      for (int d = 1; d < 64; d <<= 1) vv += __shfl_xor(vv, d);
      if (lane == 0) reds[wid * 16 + o] = vv;
    }
    __syncthreads();
    if (t < 16) sv[t] = (reds[t] + reds[16 + t] + reds[32 + t] + reds[48 + t]) / z;
    __syncthreads();
    float vsc[16]; float sq = 0.f;
#pragma unroll
    for (int o = 0; o < 16; ++o) { vsc[o] = sv[o]; sq += sv[o] * sv[o]; }
    scale = sq / ((1.f + sq) * sqrtf(sq + EPSF));
    if (it < 2) {
#pragma unroll
      for (int j = 0; j < 5; ++j) if (valid[j]) {
        float dot = 0.f;
#pragma unroll
        for (int o = 0; o < 16; ++o) dot = fmaf(xh[j][o], vsc[o] * scale, dot);
        bn[j] += dot;
      }
    }
    __syncthreads();
  }
  if (t < 16) vout[((size_t)c * 256 + b) * 16 + t] = sv[t] * scale;
}

// ---------------- class scores, softmax, argmax(first-max), mask. grid 256 (b).
__global__ __launch_bounds__(256) void classify_kernel(
    const float* __restrict__ v, float* __restrict__ probs, float* __restrict__ masked)
{
  int b = blockIdx.x, t = threadIdx.x;
  __shared__ float sc[10], vv[160];
  int c = t >> 4, o = t & 15;
  float val = 0.f;
  if (t < 160) { val = v[((size_t)c * 256 + b) * 16 + o]; vv[t] = val; }
  float sq = val * val;
  sq += __shfl_xor(sq, 1); sq += __shfl_xor(sq, 2);
  sq += __shfl_xor(sq, 4); sq += __shfl_xor(sq, 8);
  if (t < 160 && o == 0) sc[c] = sqrtf(sq + EPSF);
  __syncthreads();
  float m = sc[0];
#pragma unroll
  for (int i = 1; i < 10; ++i) m = fmaxf(m, sc[i]);
  float ee[10]; float Z = 0.f;
#pragma unroll
  for (int i = 0; i < 10; ++i) { ee[i] = expf(sc[i] - m); Z += ee[i]; }
  float p[10];
#pragma unroll
  for (int i = 0; i < 10; ++i) p[i] = ee[i] / Z;
  int label = 0; float best = p[0];
#pragma unroll
  for (int i = 1; i < 10; ++i) if (p[i] > best) { best = p[i]; label = i; }
  if (t < 10) probs[(size_t)b * 10 + t] = p[t];
  if (t < 160) masked[(size_t)b * 160 + t] = (c == label) ? vv[t] : 0.f;
}

// ---------------- decoder GEMM: C[M=256,N] = act(A[M,K] @ W[K,N] + bias). ACT 0=relu 1=sigmoid
template <int ACT>
__global__ __launch_bounds__(256) void mlp_kernel(
    const float* __restrict__ A, const float* __restrict__ W,
    const float* __restrict__ bias, float* __restrict__ C, int N, int K)
{
  int j = blockIdx.x * 64 + (threadIdx.x & 63);
  int ty = threadIdx.x >> 6;
  int m0 = blockIdx.y * 16;
  __shared__ float As[16][33];
  float acc[4] = {0.f, 0.f, 0.f, 0.f};
  for (int k0 = 0; k0 < K; k0 += 32) {
    for (int e = threadIdx.x; e < 512; e += 256) {
      int r = e >> 5, kk = e & 31;
      As[r][kk] = A[(size_t)(m0 + r) * K + k0 + kk];
    }
    __syncthreads();
    if (j < N) {
      for (int kk = 0; kk < 32; ++kk) {
        float wv = W[(size_t)(k0 + kk) * N + j];
#pragma unroll
        for (int r = 0; r < 4; ++r) acc[r] = fmaf(As[ty + 4 * r][kk], wv, acc[r]);
      }
    }
    __syncthreads();
  }
  if (j < N) {
    float bv = bias[j];
#pragma unroll
    for (int r = 0; r < 4; ++r) {
      float xx = acc[r] + bv;
      if (ACT == 0) xx = fmaxf(xx, 0.f);
      else xx = 1.f / (1.f + expf(-xx));
      C[(size_t)(m0 + ty + 4 * r) * N + j] = xx;
    }
  }
}

extern "C" void kernel_launch(void* const* d_in, const int* in_sizes, int n_in,
                              void* d_out, int out_size, void* d_ws, size_t ws_size,
                              hipStream_t stream)
{
  const float* x   = (const float*)d_in[0];
  const float* cw  = (const float*)d_in[1];
  const float* cb  = (const float*)d_in[2];
  const float* c1w = (const float*)d_in[3];
  const float* c1b = (const float*)d_in[4];
  const float* c2w = (const float*)d_in[5];
  const float* w1  = (const float*)d_in[6];
  const float* b1  = (const float*)d_in[7];
  const float* w2  = (const float*)d_in[8];
  const float* b2  = (const float*)d_in[9];
  const float* w3  = (const float*)d_in[10];
  const float* b3  = (const float*)d_in[11];
  float* out = (float*)d_out;

  char* p = (char*)d_ws;
  // xh[10][256][1152][16] fp32 (189MB) ALIASES [0..189MB): h2x, w2k, head of partial —
  // all dead before xhat_kernel runs (stream-ordered). Totals ~213MB as proven.
  float* xh = (float*)p;
  ushort_t* h2x = (ushort_t*)p; p += (size_t)52428800 * 2;   // 400*256*512 (pix-major)
  ushort_t* w2k = (ushort_t*)p; p += (size_t)10616832 * 2;   // 256*81*512
  float* partial = (float*)p;   p += (size_t)8 * 2359296 * 4;
  float* u       = (float*)p;   p += (size_t)2359296 * 4;
  float* v       = (float*)p;   p += (size_t)40960 * 4;
  float* masked  = (float*)p;   p += (size_t)40960 * 4;
  float* a1      = (float*)p;   p += (size_t)131072 * 4;
  float* a2      = (float*)p;   p += (size_t)262144 * 4;

  hipLaunchKernelGGL(w2k_prep_kernel, dim3(256), dim3(256), 0, stream, c1w, w2k);
  hipLaunchKernelGGL(conv1_kernel, dim3(20, 256), dim3(256), 0, stream, x, cw, cb, h2x);
  hipLaunchKernelGGL(caps1_mfma_kernel, dim3(1152), dim3(256), 0, stream, h2x, w2k, partial);
  hipLaunchKernelGGL(combine_kernel, dim3(1152), dim3(256), 0, stream, partial, c1b, u);
  hipLaunchKernelGGL(xhat_kernel, dim3(576), dim3(320), 0, stream, u, c2w, xh);
  hipLaunchKernelGGL(routing_kernel, dim3(256, 10), dim3(256), 0, stream, xh, v);
  hipLaunchKernelGGL(classify_kernel, dim3(256), dim3(256), 0, stream, v, out, masked);
  hipLaunchKernelGGL(mlp_kernel<0>, dim3(8, 16), dim3(256), 0, stream, masked, w1, b1, a1, 512, 160);
  hipLaunchKernelGGL(mlp_kernel<0>, dim3(16, 16), dim3(256), 0, stream, a1, w2, b2, a2, 1024, 512);
  hipLaunchKernelGGL(mlp_kernel<1>, dim3(13, 16), dim3(256), 0, stream, a2, w3, b3, out + 2560, 784, 1024);
}